// Round 14
// baseline (57.775 us; speedup 1.0000x reference)
//
#include <hip/hip_runtime.h>
#include <math.h>

// Gaussian KDE, n=12000. 3 dispatches, truncated + bin-sorted algorithm:
//   1) sel_k 1x1024: stats+min/max; EXACT Q25/Q75 via value-linear 2048-bin
//      histogram + candidate rank-select; h; FUSED scatter-emit (linear reads,
//      scattered stores) producing bin-granular-sorted es/ws/perm; per-tile
//      j-ranges computed from cum[] by constant bin-delta (no binary search).
//   2) kde_k grid(47,32)x256: tile=256 sorted i's (II=4), slice y of the
//      tile's live j-range staged in LDS; a += ws_j * exp2(-(e_i-e_j)^2).
//      Pairs beyond CUT=4.0 e-units (term < 2^-16) skipped at bin granularity.
//   3) fin_k 47x256: p = sum_{y<32} partial; out[perm[si]] = log(p + 1e-10).

#define BLK 256
#define YWK 32
#define MAXS 384
#define MAXN 12032
#define NB 2048
#define CAND 128
#define MAXIB 64
#define CUT 4.0f

#if defined(__has_builtin)
#if __has_builtin(__builtin_amdgcn_exp2f)
#define EXP2(x) __builtin_amdgcn_exp2f(x)
#endif
#endif
#ifndef EXP2
#define EXP2(x) exp2f(x)
#endif

__global__ __launch_bounds__(1024) void sel_k(const float* __restrict__ d,
                                              const float* __restrict__ w,
                                              float* __restrict__ es,
                                              float* __restrict__ wsg,
                                              int* __restrict__ perm,
                                              int2* __restrict__ tileJ,
                                              int n, int nmax, int IB) {
    __shared__ float sdata[MAXN];    // 48.1 KB
    __shared__ int hist[NB];         // 8 KB (counts -> scatter cursors)
    __shared__ int cum[NB];          // 8 KB inclusive cums
    __shared__ float cand[4][CAND];  // 2 KB
    __shared__ int sblo[MAXIB], sbhi[MAXIB];
    __shared__ int ccnt[4];
    __shared__ int tb[4], tprev[4];
    __shared__ float4 sstat[16];
    __shared__ float2 smm[16];
    __shared__ int wtot[16];
    __shared__ float sq[4];
    __shared__ float sparams[2];
    __shared__ int sdb;
    __shared__ float slh[2];

    const int t = threadIdx.x, lane = t & 63, wid = t >> 6;

    for (int b = t; b < NB; b += 1024) hist[b] = 0;
    if (t < 4) ccnt[t] = 0;

    // ---- pass 1: stage d; stats + min/max ----
    float s1 = 0.f, s2 = 0.f, sd = 0.f, sd2 = 0.f;
    float mn = __int_as_float(0x7f800000), mx = __int_as_float(0xff800000);
    for (int i = t; i < n; i += 1024) {
        float dv = d[i], wv = w[i];
        sdata[i] = dv;
        s1 += wv; s2 += wv * wv; sd += dv; sd2 += dv * dv;
        mn = fminf(mn, dv); mx = fmaxf(mx, dv);
    }
    for (int off = 32; off > 0; off >>= 1) {
        s1 += __shfl_down(s1, off); s2 += __shfl_down(s2, off);
        sd += __shfl_down(sd, off); sd2 += __shfl_down(sd2, off);
        mn = fminf(mn, __shfl_down(mn, off));
        mx = fmaxf(mx, __shfl_down(mx, off));
    }
    if (lane == 0) { sstat[wid] = make_float4(s1, s2, sd, sd2); smm[wid] = make_float2(mn, mx); }
    __syncthreads();
    if (t == 0) {
        float lo = smm[0].x, hi = smm[0].y;
        for (int q = 1; q < 16; ++q) { lo = fminf(lo, smm[q].x); hi = fmaxf(hi, smm[q].y); }
        slh[0] = lo; slh[1] = hi;
    }
    __syncthreads();
    const float lo = slh[0];
    const float range = slh[1] - lo;
    const float scale = (range > 0.f) ? (float)NB / range : 0.f;

    // ---- pass 2: value-linear histogram ----
    for (int i = t; i < n; i += 1024) {
        int b = (int)((sdata[i] - lo) * scale);
        atomicAdd(&hist[b < NB ? b : NB - 1], 1);
    }
    __syncthreads();

    // ---- inclusive scan hist -> cum (hist preserved) ----
    {
        const int b0 = t * 2;
        int a0 = hist[b0], a1 = hist[b0 + 1];
        int seg = a0 + a1, v = seg;
        for (int off = 1; off < 64; off <<= 1) {
            int u = __shfl_up(v, off);
            if (lane >= off) v += u;
        }
        if (lane == 63) wtot[wid] = v;
        __syncthreads();
        if (t == 0) {
            int acc = 0;
            for (int q = 0; q < 16; ++q) { int tmp = wtot[q]; wtot[q] = acc; acc += tmp; }
        }
        __syncthreads();
        int excl = wtot[wid] + (v - seg);
        cum[b0] = excl + a0;
        cum[b0 + 1] = excl + a0 + a1;
        __syncthreads();
    }

    // ---- quantile target bins + tile boundary bins (one scan) ----
    const double p25 = 0.25 * (double)(n - 1);
    const double p75 = 0.75 * (double)(n - 1);
    const int l25 = (int)p25, l75 = (int)p75;
    const int u25 = (l25 + 1 < n) ? l25 + 1 : l25;
    const int u75 = (l75 + 1 < n) ? l75 + 1 : l75;
    const int targets[4] = {l25, u25, l75, u75};
    for (int b = t; b < NB; b += 1024) {
        int incl = cum[b], prev = b ? cum[b - 1] : 0;
        #pragma unroll
        for (int r = 0; r < 4; ++r)
            if (prev <= targets[r] && targets[r] < incl) { tb[r] = b; tprev[r] = prev; }
        for (int ib = 0; ib < IB; ++ib) {
            int r0 = ib * 256;
            int r1 = r0 + 255; if (r1 > n - 1) r1 = n - 1;
            if (prev <= r0 && r0 < incl) sblo[ib] = b;
            if (prev <= r1 && r1 < incl) sbhi[ib] = b;
        }
    }
    __syncthreads();

    // ---- candidates of target bins ----
    const int tb0 = tb[0], tb1 = tb[1], tb2 = tb[2], tb3 = tb[3];
    for (int i = t; i < n; i += 1024) {
        float dv = sdata[i];
        int b = (int)((dv - lo) * scale);
        b = b < NB ? b : NB - 1;
        if (b == tb0) { int p = atomicAdd(&ccnt[0], 1); if (p < CAND) cand[0][p] = dv; }
        if (b == tb1) { int p = atomicAdd(&ccnt[1], 1); if (p < CAND) cand[1][p] = dv; }
        if (b == tb2) { int p = atomicAdd(&ccnt[2], 1); if (p < CAND) cand[2][p] = dv; }
        if (b == tb3) { int p = atomicAdd(&ccnt[3], 1); if (p < CAND) cand[3][p] = dv; }
    }
    __syncthreads();

    // ---- exact rank-select (wave r per target): kk-th smallest of multiset,
    //      independent of arrival order ----
    if (wid < 4) {
        const int r = wid;
        const int kk = targets[r] - tprev[r];
        const int m = ccnt[r] < CAND ? ccnt[r] : CAND;
        for (int ci = lane; ci < m; ci += 64) {
            float v = cand[r][ci];
            int rk = 0, eqb = 0;
            for (int j = 0; j < m; ++j) {
                float u = cand[r][j];
                rk += (u < v);
                eqb += (u == v && j < ci);
            }
            if (rk + eqb == kk) sq[r] = v;
        }
    }
    __syncthreads();

    // ---- h + scales + bin-delta ----
    if (t == 0) {
        double S1 = 0, S2 = 0, Sd = 0, Sd2 = 0;
        for (int q = 0; q < 16; ++q) {
            float4 v = sstat[q];
            S1 += v.x; S2 += v.y; Sd += v.z; Sd2 += v.w;
        }
        double neff = S1 * S1 / S2;
        double var  = (Sd2 - Sd * Sd / (double)n) / ((double)n - 1.0);
        double sdev = sqrt(var);
        double f25 = p25 - (double)l25, f75 = p75 - (double)l75;
        double q25 = (double)sq[0] + f25 * ((double)sq[1] - (double)sq[0]);
        double q75 = (double)sq[2] + f75 * ((double)sq[3] - (double)sq[2]);
        double sig = fmin(sdev, (q75 - q25) / 1.34);
        double h = 0.9 * sig * pow(neff, -0.2);
        float rr = (float)(sqrt(0.5 * 1.4426950408889634) / h);
        sparams[0] = rr;                                                  // r
        sparams[1] = (float)(1.0 / (h * sqrt(6.283185307179586) * S1));   // wsc
        sdb = (scale > 0.f) ? (int)ceilf((CUT / rr) * scale) + 2 : NB;    // bin-delta
    }
    __syncthreads();
    const float rr = sparams[0], wsc = sparams[1];

    // ---- fused scatter-emit: linear reads, scattered (non-blocking) stores ----
    for (int b = t; b < NB; b += 1024) hist[b] = cum[b] - hist[b];  // exclusive cursors
    __syncthreads();
    for (int i = t; i < n; i += 1024) {
        float dv = sdata[i];
        int b = (int)((dv - lo) * scale);
        b = b < NB ? b : NB - 1;
        int pos = atomicAdd(&hist[b], 1);
        es[pos]  = dv * rr;
        wsg[pos] = w[i] * wsc;
        perm[pos] = i;
    }

    // ---- per-tile j-ranges from cum[] (bin-granular, conservative) ----
    if (t < IB) {
        int bL = sblo[t] - sdb;
        int bH = sbhi[t] + sdb; if (bH > NB - 1) bH = NB - 1;
        int jlo  = (bL >= 1) ? cum[bL - 1] : 0;
        int jend = cum[bH];
        int jlo4 = jlo & ~3;
        int cnt4 = ((jend + 3) & ~3) - jlo4;
        if (cnt4 < 0) cnt4 = 0;
        if (jlo4 + cnt4 > nmax) cnt4 = nmax - jlo4;
        tileJ[t] = make_int2(jlo4, cnt4);
    }
}

__global__ __launch_bounds__(BLK) void kde_k(const float* __restrict__ es,
                                             const float* __restrict__ wsg,
                                             const int2* __restrict__ tileJ,
                                             float* __restrict__ partial,
                                             int n, int nmax) {
    __shared__ float se[MAXS];       // 1.5 KB
    __shared__ float sw[MAXS];       // 1.5 KB
    __shared__ float sredf[1024];    // 4 KB
    const int t = threadIdx.x, ib = blockIdx.x, y = blockIdx.y;
    const int lane = t & 63, wv = t >> 6;

    const int2 tj = tileJ[ib];
    const int jlo = tj.x, cnt = tj.y;
    const int L = (((cnt + YWK - 1) / YWK) + 15) & ~15;   // slice len, mult of 16
    const int start = jlo + y * L;
    const int jend = jlo + cnt;

    for (int idx = t; idx < L; idx += BLK) {
        int jg = start + idx;
        bool ok = (jg < jend) && (jg < n);   // slots >= n never written: exclude
        se[idx] = ok ? es[jg] : 1e30f;
        sw[idx] = ok ? wsg[jg] : 0.f;
    }
    const int i0 = ib * 256 + lane;
    // rows si >= n are dead (fin skips); es there is unwritten scratch -> clamp
    float ei0 = (i0       < n) ? es[i0]       : 0.f;
    float ei1 = (i0 + 64  < n) ? es[i0 + 64]  : 0.f;
    float ei2 = (i0 + 128 < n) ? es[i0 + 128] : 0.f;
    float ei3 = (i0 + 192 < n) ? es[i0 + 192] : 0.f;
    __syncthreads();

    float a0 = 0.f, a1 = 0.f, a2 = 0.f, a3 = 0.f;
    if (L > 0) {
        const int q4 = L >> 2;                     // elements per wave quarter
        const float4* pe = (const float4*)(se + wv * q4);
        const float4* pw = (const float4*)(sw + wv * q4);
        const int nq = L >> 4;                     // float4s per wave quarter
        for (int jj = 0; jj < nq; ++jj) {
            float4 e4 = pe[jj];
            float4 w4 = pw[jj];
            { float u = ei0 - e4.x, v = ei0 - e4.y, x = ei0 - e4.z, z = ei0 - e4.w;
              a0 = fmaf(w4.x, EXP2(-(u * u)), a0); a0 = fmaf(w4.y, EXP2(-(v * v)), a0);
              a0 = fmaf(w4.z, EXP2(-(x * x)), a0); a0 = fmaf(w4.w, EXP2(-(z * z)), a0); }
            { float u = ei1 - e4.x, v = ei1 - e4.y, x = ei1 - e4.z, z = ei1 - e4.w;
              a1 = fmaf(w4.x, EXP2(-(u * u)), a1); a1 = fmaf(w4.y, EXP2(-(v * v)), a1);
              a1 = fmaf(w4.z, EXP2(-(x * x)), a1); a1 = fmaf(w4.w, EXP2(-(z * z)), a1); }
            { float u = ei2 - e4.x, v = ei2 - e4.y, x = ei2 - e4.z, z = ei2 - e4.w;
              a2 = fmaf(w4.x, EXP2(-(u * u)), a2); a2 = fmaf(w4.y, EXP2(-(v * v)), a2);
              a2 = fmaf(w4.z, EXP2(-(x * x)), a2); a2 = fmaf(w4.w, EXP2(-(z * z)), a2); }
            { float u = ei3 - e4.x, v = ei3 - e4.y, x = ei3 - e4.z, z = ei3 - e4.w;
              a3 = fmaf(w4.x, EXP2(-(u * u)), a3); a3 = fmaf(w4.y, EXP2(-(v * v)), a3);
              a3 = fmaf(w4.z, EXP2(-(x * x)), a3); a3 = fmaf(w4.w, EXP2(-(z * z)), a3); }
        }
    }
    __syncthreads();
    sredf[wv * 256 +       lane] = a0;
    sredf[wv * 256 +  64 + lane] = a1;
    sredf[wv * 256 + 128 + lane] = a2;
    sredf[wv * 256 + 192 + lane] = a3;
    __syncthreads();
    partial[y * nmax + ib * 256 + t] =
        sredf[t] + sredf[256 + t] + sredf[512 + t] + sredf[768 + t];
}

__global__ __launch_bounds__(BLK) void fin_k(const float* __restrict__ partial,
                                             const int* __restrict__ perm,
                                             float* __restrict__ out, int n, int nmax) {
    int si = blockIdx.x * BLK + threadIdx.x;
    if (si < n) {
        float p = 0.f;
        #pragma unroll
        for (int y = 0; y < YWK; ++y) p += partial[y * nmax + si];
        out[perm[si]] = logf(p + 1e-10f);
    }
}

extern "C" void kernel_launch(void* const* d_in, const int* in_sizes, int n_in,
                              void* d_out, int out_size, void* d_ws, size_t ws_size,
                              hipStream_t stream) {
    const float* d = (const float*)d_in[0];
    const float* w = (const float*)d_in[1];
    float* out = (float*)d_out;
    const int n = in_sizes[0];

    const int nmax = ((n + 255) / 256) * 256;   // 12032
    const int IB = nmax / 256;                  // 47

    // ws layout (float units): es[nmax] | wsg[nmax] | perm int[nmax] |
    //                          tileJ int2[64] | partial float[YWK*nmax]
    float* wsf     = (float*)d_ws;
    float* es      = wsf;
    float* wsg     = wsf + nmax;
    int*   perm    = (int*)(wsf + 2 * nmax);
    int2*  tileJ   = (int2*)(wsf + 3 * nmax);
    float* partial = wsf + 3 * nmax + 128;

    sel_k<<<1, 1024, 0, stream>>>(d, w, es, wsg, perm, tileJ, n, nmax, IB);
    dim3 grid(IB, YWK);
    kde_k<<<grid, BLK, 0, stream>>>(es, wsg, tileJ, partial, n, nmax);
    fin_k<<<IB, BLK, 0, stream>>>(partial, perm, out, n, nmax);
}

// Round 15
// 44.499 us; speedup vs baseline: 1.2983x; 1.2983x over previous
//
#include <hip/hip_runtime.h>
#include <math.h>

// Gaussian KDE, n=12000. 4 dispatches, truncated + bin-sorted algorithm:
//   1) selA 1x1024: stats+min/max; EXACT Q25/Q75 via value-linear 2048-bin
//      histogram + candidate rank-select; h; writes params, exclusive cursors
//      (gcur), and per-tile j-ranges (pure cum[] arithmetic).
//   2) selB 47x256: parallel scatter-emit -- one i per thread, coalesced
//      reads, pos = global atomicAdd(cursor[bin]), packed float2 store.
//      Scatter spread across 47 CUs (R14 lesson: 36K scattered stores from
//      ONE CU serialize ~15-35us; across 47 CUs they are ~1us).
//   3) kde_k grid(47,32)x256: tile=256 sorted i's (II=4), slice y of the
//      tile's live j-range staged in LDS; a += ws_j * exp2(-(e_i-e_j)^2).
//      Pairs beyond CUT=4.0 e-units (term < 2^-16) skipped at bin granularity.
//   4) fin_k 47x256: p = sum_{y<32} partial; out[perm[si]] = log(p + 1e-10).

#define BLK 256
#define YWK 32
#define MAXS 384
#define MAXN 12032
#define NB 2048
#define CAND 128
#define MAXIB 64
#define CUT 4.0f

#if defined(__has_builtin)
#if __has_builtin(__builtin_amdgcn_exp2f)
#define EXP2(x) __builtin_amdgcn_exp2f(x)
#endif
#endif
#ifndef EXP2
#define EXP2(x) exp2f(x)
#endif

// params layout (floats): [0]=lo [1]=scale [2]=rr [3]=wsc
__global__ __launch_bounds__(1024) void selA(const float* __restrict__ d,
                                             const float* __restrict__ w,
                                             float* __restrict__ params,
                                             int* __restrict__ gcur,
                                             int2* __restrict__ tileJ,
                                             int n, int nmax, int IB) {
    __shared__ float sdata[MAXN];    // 48.1 KB
    __shared__ int hist[NB];         // 8 KB
    __shared__ int cum[NB];          // 8 KB
    __shared__ float cand[4][CAND];  // 2 KB
    __shared__ int sblo[MAXIB], sbhi[MAXIB];
    __shared__ int ccnt[4];
    __shared__ int tb[4], tprev[4];
    __shared__ float4 sstat[16];
    __shared__ float2 smm[16];
    __shared__ int wtot[16];
    __shared__ float sq[4];
    __shared__ float sparams[2];
    __shared__ int sdb;
    __shared__ float slh[2];

    const int t = threadIdx.x, lane = t & 63, wid = t >> 6;

    for (int b = t; b < NB; b += 1024) hist[b] = 0;
    if (t < 4) ccnt[t] = 0;

    // ---- pass 1: stage d; stats + min/max ----
    float s1 = 0.f, s2 = 0.f, sd = 0.f, sd2 = 0.f;
    float mn = __int_as_float(0x7f800000), mx = __int_as_float(0xff800000);
    for (int i = t; i < n; i += 1024) {
        float dv = d[i], wv = w[i];
        sdata[i] = dv;
        s1 += wv; s2 += wv * wv; sd += dv; sd2 += dv * dv;
        mn = fminf(mn, dv); mx = fmaxf(mx, dv);
    }
    for (int off = 32; off > 0; off >>= 1) {
        s1 += __shfl_down(s1, off); s2 += __shfl_down(s2, off);
        sd += __shfl_down(sd, off); sd2 += __shfl_down(sd2, off);
        mn = fminf(mn, __shfl_down(mn, off));
        mx = fmaxf(mx, __shfl_down(mx, off));
    }
    if (lane == 0) { sstat[wid] = make_float4(s1, s2, sd, sd2); smm[wid] = make_float2(mn, mx); }
    __syncthreads();
    if (t == 0) {
        float lo = smm[0].x, hi = smm[0].y;
        for (int q = 1; q < 16; ++q) { lo = fminf(lo, smm[q].x); hi = fmaxf(hi, smm[q].y); }
        slh[0] = lo; slh[1] = hi;
    }
    __syncthreads();
    const float lo = slh[0];
    const float range = slh[1] - lo;
    const float scale = (range > 0.f) ? (float)NB / range : 0.f;

    // ---- pass 2: value-linear histogram ----
    for (int i = t; i < n; i += 1024) {
        int b = (int)((sdata[i] - lo) * scale);
        atomicAdd(&hist[b < NB ? b : NB - 1], 1);
    }
    __syncthreads();

    // ---- inclusive scan hist -> cum ----
    {
        const int b0 = t * 2;
        int a0 = hist[b0], a1 = hist[b0 + 1];
        int seg = a0 + a1, v = seg;
        for (int off = 1; off < 64; off <<= 1) {
            int u = __shfl_up(v, off);
            if (lane >= off) v += u;
        }
        if (lane == 63) wtot[wid] = v;
        __syncthreads();
        if (t == 0) {
            int acc = 0;
            for (int q = 0; q < 16; ++q) { int tmp = wtot[q]; wtot[q] = acc; acc += tmp; }
        }
        __syncthreads();
        int excl = wtot[wid] + (v - seg);
        cum[b0] = excl + a0;
        cum[b0 + 1] = excl + a0 + a1;
        __syncthreads();
    }

    // ---- quantile target bins + tile boundary bins ----
    const double p25 = 0.25 * (double)(n - 1);
    const double p75 = 0.75 * (double)(n - 1);
    const int l25 = (int)p25, l75 = (int)p75;
    const int u25 = (l25 + 1 < n) ? l25 + 1 : l25;
    const int u75 = (l75 + 1 < n) ? l75 + 1 : l75;
    const int targets[4] = {l25, u25, l75, u75};
    for (int b = t; b < NB; b += 1024) {
        int incl = cum[b], prev = b ? cum[b - 1] : 0;
        #pragma unroll
        for (int r = 0; r < 4; ++r)
            if (prev <= targets[r] && targets[r] < incl) { tb[r] = b; tprev[r] = prev; }
        for (int ib = 0; ib < IB; ++ib) {
            int r0 = ib * 256;
            int r1 = r0 + 255; if (r1 > n - 1) r1 = n - 1;
            if (prev <= r0 && r0 < incl) sblo[ib] = b;
            if (prev <= r1 && r1 < incl) sbhi[ib] = b;
        }
    }
    __syncthreads();

    // ---- candidates of target bins ----
    const int tb0 = tb[0], tb1 = tb[1], tb2 = tb[2], tb3 = tb[3];
    for (int i = t; i < n; i += 1024) {
        float dv = sdata[i];
        int b = (int)((dv - lo) * scale);
        b = b < NB ? b : NB - 1;
        if (b == tb0) { int p = atomicAdd(&ccnt[0], 1); if (p < CAND) cand[0][p] = dv; }
        if (b == tb1) { int p = atomicAdd(&ccnt[1], 1); if (p < CAND) cand[1][p] = dv; }
        if (b == tb2) { int p = atomicAdd(&ccnt[2], 1); if (p < CAND) cand[2][p] = dv; }
        if (b == tb3) { int p = atomicAdd(&ccnt[3], 1); if (p < CAND) cand[3][p] = dv; }
    }
    __syncthreads();

    // ---- exact rank-select (wave r per target): kk-th smallest of multiset ----
    if (wid < 4) {
        const int r = wid;
        const int kk = targets[r] - tprev[r];
        const int m = ccnt[r] < CAND ? ccnt[r] : CAND;
        for (int ci = lane; ci < m; ci += 64) {
            float v = cand[r][ci];
            int rk = 0, eqb = 0;
            for (int j = 0; j < m; ++j) {
                float u = cand[r][j];
                rk += (u < v);
                eqb += (u == v && j < ci);
            }
            if (rk + eqb == kk) sq[r] = v;
        }
    }
    __syncthreads();

    // ---- h + scales + bin-delta ----
    if (t == 0) {
        double S1 = 0, S2 = 0, Sd = 0, Sd2 = 0;
        for (int q = 0; q < 16; ++q) {
            float4 v = sstat[q];
            S1 += v.x; S2 += v.y; Sd += v.z; Sd2 += v.w;
        }
        double neff = S1 * S1 / S2;
        double var  = (Sd2 - Sd * Sd / (double)n) / ((double)n - 1.0);
        double sdev = sqrt(var);
        double f25 = p25 - (double)l25, f75 = p75 - (double)l75;
        double q25 = (double)sq[0] + f25 * ((double)sq[1] - (double)sq[0]);
        double q75 = (double)sq[2] + f75 * ((double)sq[3] - (double)sq[2]);
        double sig = fmin(sdev, (q75 - q25) / 1.34);
        double h = 0.9 * sig * pow(neff, -0.2);
        float rr = (float)(sqrt(0.5 * 1.4426950408889634) / h);
        sparams[0] = rr;
        sparams[1] = (float)(1.0 / (h * sqrt(6.283185307179586) * S1));
        sdb = (scale > 0.f) ? (int)ceilf((CUT / rr) * scale) + 2 : NB;
        params[0] = lo; params[1] = scale;
        params[2] = rr; params[3] = sparams[1];
    }
    __syncthreads();

    // ---- emit exclusive cursors to global (coalesced) ----
    for (int b = t; b < NB; b += 1024) gcur[b] = cum[b] - hist[b];

    // ---- per-tile j-ranges from cum[] (bin-granular, conservative) ----
    if (t < IB) {
        int bL = sblo[t] - sdb;
        int bH = sbhi[t] + sdb; if (bH > NB - 1) bH = NB - 1;
        int jlo  = (bL >= 1) ? cum[bL - 1] : 0;
        int jend = cum[bH];
        int jlo4 = jlo & ~3;
        int cnt4 = ((jend + 3) & ~3) - jlo4;
        if (cnt4 < 0) cnt4 = 0;
        if (jlo4 + cnt4 > nmax) cnt4 = nmax - jlo4;
        tileJ[t] = make_int2(jlo4, cnt4);
    }
}

__global__ __launch_bounds__(BLK) void selB(const float* __restrict__ d,
                                            const float* __restrict__ w,
                                            const float* __restrict__ params,
                                            int* __restrict__ gcur,
                                            float2* __restrict__ esw,
                                            int* __restrict__ perm,
                                            int n) {
    const int i = blockIdx.x * BLK + threadIdx.x;
    if (i >= n) return;
    const float lo = params[0], scale = params[1];
    const float rr = params[2], wsc = params[3];
    float dv = d[i];
    int b = (int)((dv - lo) * scale);
    b = b < NB ? b : NB - 1;
    int pos = atomicAdd(&gcur[b], 1);          // device-scope, spread over 47 CUs
    esw[pos] = make_float2(dv * rr, w[i] * wsc);
    perm[pos] = i;
}

__global__ __launch_bounds__(BLK) void kde_k(const float2* __restrict__ esw,
                                             const int2* __restrict__ tileJ,
                                             float* __restrict__ partial,
                                             int n, int nmax) {
    __shared__ float se[MAXS];       // 1.5 KB
    __shared__ float sw[MAXS];       // 1.5 KB
    __shared__ float sredf[1024];    // 4 KB
    const int t = threadIdx.x, ib = blockIdx.x, y = blockIdx.y;
    const int lane = t & 63, wv = t >> 6;

    const int2 tj = tileJ[ib];
    const int jlo = tj.x, cnt = tj.y;
    const int L = (((cnt + YWK - 1) / YWK) + 15) & ~15;   // slice len, mult of 16
    const int start = jlo + y * L;
    const int jend = jlo + cnt;

    for (int idx = t; idx < L; idx += BLK) {
        int jg = start + idx;
        bool ok = (jg < jend) && (jg < n);   // slots >= n never written
        float2 v = ok ? esw[jg] : make_float2(1e30f, 0.f);
        se[idx] = v.x;
        sw[idx] = v.y;
    }
    const int i0 = ib * 256 + lane;
    float ei0 = (i0       < n) ? esw[i0].x       : 0.f;
    float ei1 = (i0 + 64  < n) ? esw[i0 + 64].x  : 0.f;
    float ei2 = (i0 + 128 < n) ? esw[i0 + 128].x : 0.f;
    float ei3 = (i0 + 192 < n) ? esw[i0 + 192].x : 0.f;
    __syncthreads();

    float a0 = 0.f, a1 = 0.f, a2 = 0.f, a3 = 0.f;
    if (L > 0) {
        const int q4 = L >> 2;
        const float4* pe = (const float4*)(se + wv * q4);
        const float4* pw = (const float4*)(sw + wv * q4);
        const int nq = L >> 4;
        for (int jj = 0; jj < nq; ++jj) {
            float4 e4 = pe[jj];
            float4 w4 = pw[jj];
            { float u = ei0 - e4.x, v = ei0 - e4.y, x = ei0 - e4.z, z = ei0 - e4.w;
              a0 = fmaf(w4.x, EXP2(-(u * u)), a0); a0 = fmaf(w4.y, EXP2(-(v * v)), a0);
              a0 = fmaf(w4.z, EXP2(-(x * x)), a0); a0 = fmaf(w4.w, EXP2(-(z * z)), a0); }
            { float u = ei1 - e4.x, v = ei1 - e4.y, x = ei1 - e4.z, z = ei1 - e4.w;
              a1 = fmaf(w4.x, EXP2(-(u * u)), a1); a1 = fmaf(w4.y, EXP2(-(v * v)), a1);
              a1 = fmaf(w4.z, EXP2(-(x * x)), a1); a1 = fmaf(w4.w, EXP2(-(z * z)), a1); }
            { float u = ei2 - e4.x, v = ei2 - e4.y, x = ei2 - e4.z, z = ei2 - e4.w;
              a2 = fmaf(w4.x, EXP2(-(u * u)), a2); a2 = fmaf(w4.y, EXP2(-(v * v)), a2);
              a2 = fmaf(w4.z, EXP2(-(x * x)), a2); a2 = fmaf(w4.w, EXP2(-(z * z)), a2); }
            { float u = ei3 - e4.x, v = ei3 - e4.y, x = ei3 - e4.z, z = ei3 - e4.w;
              a3 = fmaf(w4.x, EXP2(-(u * u)), a3); a3 = fmaf(w4.y, EXP2(-(v * v)), a3);
              a3 = fmaf(w4.z, EXP2(-(x * x)), a3); a3 = fmaf(w4.w, EXP2(-(z * z)), a3); }
        }
    }
    __syncthreads();
    sredf[wv * 256 +       lane] = a0;
    sredf[wv * 256 +  64 + lane] = a1;
    sredf[wv * 256 + 128 + lane] = a2;
    sredf[wv * 256 + 192 + lane] = a3;
    __syncthreads();
    partial[y * nmax + ib * 256 + t] =
        sredf[t] + sredf[256 + t] + sredf[512 + t] + sredf[768 + t];
}

__global__ __launch_bounds__(BLK) void fin_k(const float* __restrict__ partial,
                                             const int* __restrict__ perm,
                                             float* __restrict__ out, int n, int nmax) {
    int si = blockIdx.x * BLK + threadIdx.x;
    if (si < n) {
        float p = 0.f;
        #pragma unroll
        for (int y = 0; y < YWK; ++y) p += partial[y * nmax + si];
        out[perm[si]] = logf(p + 1e-10f);
    }
}

extern "C" void kernel_launch(void* const* d_in, const int* in_sizes, int n_in,
                              void* d_out, int out_size, void* d_ws, size_t ws_size,
                              hipStream_t stream) {
    const float* d = (const float*)d_in[0];
    const float* w = (const float*)d_in[1];
    float* out = (float*)d_out;
    const int n = in_sizes[0];

    const int nmax = ((n + 255) / 256) * 256;   // 12032
    const int IB = nmax / 256;                  // 47

    // ws layout (float units): esw float2[nmax] | perm int[nmax] |
    //   params[4+pad=16] | gcur int[NB] | tileJ int2[64] | partial[YWK*nmax]
    float*  wsf     = (float*)d_ws;
    float2* esw     = (float2*)wsf;
    int*    perm    = (int*)(wsf + 2 * nmax);
    float*  params  = wsf + 3 * nmax;
    int*    gcur    = (int*)(wsf + 3 * nmax + 16);
    int2*   tileJ   = (int2*)(wsf + 3 * nmax + 16 + NB);
    float*  partial = wsf + 3 * nmax + 16 + NB + 128;

    selA<<<1, 1024, 0, stream>>>(d, w, params, gcur, tileJ, n, nmax, IB);
    selB<<<IB, BLK, 0, stream>>>(d, w, params, gcur, esw, perm, n);
    dim3 grid(IB, YWK);
    kde_k<<<grid, BLK, 0, stream>>>(esw, tileJ, partial, n, nmax);
    fin_k<<<IB, BLK, 0, stream>>>(partial, perm, out, n, nmax);
}

// Round 16
// 36.537 us; speedup vs baseline: 1.5813x; 1.2179x over previous
//
#include <hip/hip_runtime.h>
#include <math.h>

// Gaussian KDE, n=12000. 4 dispatches, truncated + bin-sorted algorithm:
//   1) selA 1x1024: stats+min/max; EXACT Q25/Q75 via value-linear 2048-bin
//      histogram + candidate rank-select; h (float transcendentals); params,
//      exclusive cursors (gcur), per-tile j-ranges via binary search on cum.
//   2) selB 47x256: parallel scatter-emit -- one i per thread, coalesced
//      reads, pos = global atomicAdd(cursor[bin]), packed float2 store.
//   3) kde_k grid(47,32)x256: tile=256 sorted i's (II=4), slice y of the
//      tile's live j-range staged in LDS; a += ws_j * exp2(-(e_i-e_j)^2).
//      Pairs beyond CUT=4.0 e-units (term < 2^-16) skipped at bin granularity.
//   4) fin_k 47x256: p = sum_{y<32} partial; out[perm[si]] = log(p + 1e-10).

#define BLK 256
#define YWK 32
#define MAXS 384
#define MAXN 12032
#define NB 2048
#define CAND 128
#define CUT 4.0f

#if defined(__has_builtin)
#if __has_builtin(__builtin_amdgcn_exp2f)
#define EXP2(x) __builtin_amdgcn_exp2f(x)
#endif
#endif
#ifndef EXP2
#define EXP2(x) exp2f(x)
#endif

// params layout (floats): [0]=lo [1]=scale [2]=rr [3]=wsc
__global__ __launch_bounds__(1024) void selA(const float* __restrict__ d,
                                             const float* __restrict__ w,
                                             float* __restrict__ params,
                                             int* __restrict__ gcur,
                                             int2* __restrict__ tileJ,
                                             int n, int nmax, int IB) {
    __shared__ float sdata[MAXN];    // 48.1 KB
    __shared__ int hist[NB];         // 8 KB
    __shared__ int cum[NB];          // 8 KB
    __shared__ float cand[4][CAND];  // 2 KB
    __shared__ int ccnt[4];
    __shared__ int tb[4], tprev[4];
    __shared__ float4 sstat[16];
    __shared__ float2 smm[16];
    __shared__ int wtot[16];
    __shared__ float sq[4];
    __shared__ float sparams[2];
    __shared__ int sdb;
    __shared__ float slh[2];

    const int t = threadIdx.x, lane = t & 63, wid = t >> 6;

    for (int b = t; b < NB; b += 1024) hist[b] = 0;
    if (t < 4) ccnt[t] = 0;

    // ---- pass 1: stage d; stats + min/max ----
    float s1 = 0.f, s2 = 0.f, sd = 0.f, sd2 = 0.f;
    float mn = __int_as_float(0x7f800000), mx = __int_as_float(0xff800000);
    for (int i = t; i < n; i += 1024) {
        float dv = d[i], wv = w[i];
        sdata[i] = dv;
        s1 += wv; s2 += wv * wv; sd += dv; sd2 += dv * dv;
        mn = fminf(mn, dv); mx = fmaxf(mx, dv);
    }
    for (int off = 32; off > 0; off >>= 1) {
        s1 += __shfl_down(s1, off); s2 += __shfl_down(s2, off);
        sd += __shfl_down(sd, off); sd2 += __shfl_down(sd2, off);
        mn = fminf(mn, __shfl_down(mn, off));
        mx = fmaxf(mx, __shfl_down(mx, off));
    }
    if (lane == 0) { sstat[wid] = make_float4(s1, s2, sd, sd2); smm[wid] = make_float2(mn, mx); }
    __syncthreads();
    if (t == 0) {
        float lo = smm[0].x, hi = smm[0].y;
        for (int q = 1; q < 16; ++q) { lo = fminf(lo, smm[q].x); hi = fmaxf(hi, smm[q].y); }
        slh[0] = lo; slh[1] = hi;
    }
    __syncthreads();
    const float lo = slh[0];
    const float range = slh[1] - lo;
    const float scale = (range > 0.f) ? (float)NB / range : 0.f;

    // ---- pass 2: value-linear histogram ----
    for (int i = t; i < n; i += 1024) {
        int b = (int)((sdata[i] - lo) * scale);
        atomicAdd(&hist[b < NB ? b : NB - 1], 1);
    }
    __syncthreads();

    // ---- inclusive scan hist -> cum ----
    {
        const int b0 = t * 2;
        int a0 = hist[b0], a1 = hist[b0 + 1];
        int seg = a0 + a1, v = seg;
        for (int off = 1; off < 64; off <<= 1) {
            int u = __shfl_up(v, off);
            if (lane >= off) v += u;
        }
        if (lane == 63) wtot[wid] = v;
        __syncthreads();
        if (t == 0) {
            int acc = 0;
            for (int q = 0; q < 16; ++q) { int tmp = wtot[q]; wtot[q] = acc; acc += tmp; }
        }
        __syncthreads();
        int excl = wtot[wid] + (v - seg);
        cum[b0] = excl + a0;
        cum[b0 + 1] = excl + a0 + a1;
        __syncthreads();
    }

    // ---- quantile target bins (4 targets only; tile bounds done later) ----
    const double p25 = 0.25 * (double)(n - 1);
    const double p75 = 0.75 * (double)(n - 1);
    const int l25 = (int)p25, l75 = (int)p75;
    const int u25 = (l25 + 1 < n) ? l25 + 1 : l25;
    const int u75 = (l75 + 1 < n) ? l75 + 1 : l75;
    const int targets[4] = {l25, u25, l75, u75};
    for (int b = t; b < NB; b += 1024) {
        int incl = cum[b], prev = b ? cum[b - 1] : 0;
        #pragma unroll
        for (int r = 0; r < 4; ++r)
            if (prev <= targets[r] && targets[r] < incl) { tb[r] = b; tprev[r] = prev; }
    }
    __syncthreads();

    // ---- candidates of target bins ----
    const int tb0 = tb[0], tb1 = tb[1], tb2 = tb[2], tb3 = tb[3];
    for (int i = t; i < n; i += 1024) {
        float dv = sdata[i];
        int b = (int)((dv - lo) * scale);
        b = b < NB ? b : NB - 1;
        if (b == tb0) { int p = atomicAdd(&ccnt[0], 1); if (p < CAND) cand[0][p] = dv; }
        if (b == tb1) { int p = atomicAdd(&ccnt[1], 1); if (p < CAND) cand[1][p] = dv; }
        if (b == tb2) { int p = atomicAdd(&ccnt[2], 1); if (p < CAND) cand[2][p] = dv; }
        if (b == tb3) { int p = atomicAdd(&ccnt[3], 1); if (p < CAND) cand[3][p] = dv; }
    }
    __syncthreads();

    // ---- exact rank-select (wave r per target): kk-th smallest of multiset ----
    if (wid < 4) {
        const int r = wid;
        const int kk = targets[r] - tprev[r];
        const int m = ccnt[r] < CAND ? ccnt[r] : CAND;
        for (int ci = lane; ci < m; ci += 64) {
            float v = cand[r][ci];
            int rk = 0, eqb = 0;
            for (int j = 0; j < m; ++j) {
                float u = cand[r][j];
                rk += (u < v);
                eqb += (u == v && j < ci);
            }
            if (rk + eqb == kk) sq[r] = v;
        }
    }
    __syncthreads();

    // ---- h + scales + bin-delta (FLOAT transcendentals; double only for sums) ----
    if (t == 0) {
        double S1 = 0, S2 = 0, Sd = 0, Sd2 = 0;
        for (int q = 0; q < 16; ++q) {
            float4 v = sstat[q];
            S1 += v.x; S2 += v.y; Sd += v.z; Sd2 += v.w;
        }
        float neff = (float)(S1 * S1 / S2);
        float varf = (float)((Sd2 - Sd * Sd / (double)n) / ((double)n - 1.0));
        float sdev = sqrtf(varf);
        float f25 = (float)(p25 - (double)l25), f75 = (float)(p75 - (double)l75);
        float q25 = sq[0] + f25 * (sq[1] - sq[0]);
        float q75 = sq[2] + f75 * (sq[3] - sq[2]);
        float sig = fminf(sdev, (q75 - q25) * (1.0f / 1.34f));
        float h = 0.9f * sig * exp2f(-0.2f * log2f(neff));
        float rr = 0.84932180f / h;                       // sqrt(0.5*log2(e))/h
        sparams[0] = rr;
        sparams[1] = 1.0f / (h * 2.50662827f * (float)S1); // inv_norm / S1
        sdb = (scale > 0.f) ? (int)ceilf((CUT / rr) * scale) + 2 : NB;
        params[0] = lo; params[1] = scale;
        params[2] = rr; params[3] = sparams[1];
    }
    __syncthreads();

    // ---- emit exclusive cursors to global (coalesced) ----
    for (int b = t; b < NB; b += 1024) gcur[b] = cum[b] - hist[b];

    // ---- per-tile j-ranges: binary search cum for boundary ranks ----
    if (t < IB) {
        const int r0 = t * 256;
        int r1 = r0 + 255; if (r1 > n - 1) r1 = n - 1;
        int a = 0, bv = NB - 1;
        while (a < bv) { int m = (a + bv) >> 1; if (cum[m] > r0) bv = m; else a = m + 1; }
        const int blo = a;                       // bin containing rank r0
        a = 0; bv = NB - 1;
        while (a < bv) { int m = (a + bv) >> 1; if (cum[m] > r1) bv = m; else a = m + 1; }
        const int bhi = a;                       // bin containing rank r1
        int bL = blo - sdb;
        int bH = bhi + sdb; if (bH > NB - 1) bH = NB - 1;
        int jlo  = (bL >= 1) ? cum[bL - 1] : 0;
        int jend = cum[bH];
        int jlo4 = jlo & ~3;
        int cnt4 = ((jend + 3) & ~3) - jlo4;
        if (cnt4 < 0) cnt4 = 0;
        if (jlo4 + cnt4 > nmax) cnt4 = nmax - jlo4;
        tileJ[t] = make_int2(jlo4, cnt4);
    }
}

__global__ __launch_bounds__(BLK) void selB(const float* __restrict__ d,
                                            const float* __restrict__ w,
                                            const float* __restrict__ params,
                                            int* __restrict__ gcur,
                                            float2* __restrict__ esw,
                                            int* __restrict__ perm,
                                            int n) {
    const int i = blockIdx.x * BLK + threadIdx.x;
    if (i >= n) return;
    const float lo = params[0], scale = params[1];
    const float rr = params[2], wsc = params[3];
    float dv = d[i];
    int b = (int)((dv - lo) * scale);
    b = b < NB ? b : NB - 1;
    int pos = atomicAdd(&gcur[b], 1);          // device-scope, spread over 47 CUs
    esw[pos] = make_float2(dv * rr, w[i] * wsc);
    perm[pos] = i;
}

__global__ __launch_bounds__(BLK) void kde_k(const float2* __restrict__ esw,
                                             const int2* __restrict__ tileJ,
                                             float* __restrict__ partial,
                                             int n, int nmax) {
    __shared__ float se[MAXS];       // 1.5 KB
    __shared__ float sw[MAXS];       // 1.5 KB
    __shared__ float sredf[1024];    // 4 KB
    const int t = threadIdx.x, ib = blockIdx.x, y = blockIdx.y;
    const int lane = t & 63, wv = t >> 6;

    const int2 tj = tileJ[ib];
    const int jlo = tj.x, cnt = tj.y;
    const int L = (((cnt + YWK - 1) / YWK) + 15) & ~15;   // slice len, mult of 16
    const int start = jlo + y * L;
    const int jend = jlo + cnt;

    for (int idx = t; idx < L; idx += BLK) {
        int jg = start + idx;
        bool ok = (jg < jend) && (jg < n);   // slots >= n never written
        float2 v = ok ? esw[jg] : make_float2(1e30f, 0.f);
        se[idx] = v.x;
        sw[idx] = v.y;
    }
    const int i0 = ib * 256 + lane;
    float ei0 = (i0       < n) ? esw[i0].x       : 0.f;
    float ei1 = (i0 + 64  < n) ? esw[i0 + 64].x  : 0.f;
    float ei2 = (i0 + 128 < n) ? esw[i0 + 128].x : 0.f;
    float ei3 = (i0 + 192 < n) ? esw[i0 + 192].x : 0.f;
    __syncthreads();

    float a0 = 0.f, a1 = 0.f, a2 = 0.f, a3 = 0.f;
    if (L > 0) {
        const int q4 = L >> 2;
        const float4* pe = (const float4*)(se + wv * q4);
        const float4* pw = (const float4*)(sw + wv * q4);
        const int nq = L >> 4;
        for (int jj = 0; jj < nq; ++jj) {
            float4 e4 = pe[jj];
            float4 w4 = pw[jj];
            { float u = ei0 - e4.x, v = ei0 - e4.y, x = ei0 - e4.z, z = ei0 - e4.w;
              a0 = fmaf(w4.x, EXP2(-(u * u)), a0); a0 = fmaf(w4.y, EXP2(-(v * v)), a0);
              a0 = fmaf(w4.z, EXP2(-(x * x)), a0); a0 = fmaf(w4.w, EXP2(-(z * z)), a0); }
            { float u = ei1 - e4.x, v = ei1 - e4.y, x = ei1 - e4.z, z = ei1 - e4.w;
              a1 = fmaf(w4.x, EXP2(-(u * u)), a1); a1 = fmaf(w4.y, EXP2(-(v * v)), a1);
              a1 = fmaf(w4.z, EXP2(-(x * x)), a1); a1 = fmaf(w4.w, EXP2(-(z * z)), a1); }
            { float u = ei2 - e4.x, v = ei2 - e4.y, x = ei2 - e4.z, z = ei2 - e4.w;
              a2 = fmaf(w4.x, EXP2(-(u * u)), a2); a2 = fmaf(w4.y, EXP2(-(v * v)), a2);
              a2 = fmaf(w4.z, EXP2(-(x * x)), a2); a2 = fmaf(w4.w, EXP2(-(z * z)), a2); }
            { float u = ei3 - e4.x, v = ei3 - e4.y, x = ei3 - e4.z, z = ei3 - e4.w;
              a3 = fmaf(w4.x, EXP2(-(u * u)), a3); a3 = fmaf(w4.y, EXP2(-(v * v)), a3);
              a3 = fmaf(w4.z, EXP2(-(x * x)), a3); a3 = fmaf(w4.w, EXP2(-(z * z)), a3); }
        }
    }
    __syncthreads();
    sredf[wv * 256 +       lane] = a0;
    sredf[wv * 256 +  64 + lane] = a1;
    sredf[wv * 256 + 128 + lane] = a2;
    sredf[wv * 256 + 192 + lane] = a3;
    __syncthreads();
    partial[y * nmax + ib * 256 + t] =
        sredf[t] + sredf[256 + t] + sredf[512 + t] + sredf[768 + t];
}

__global__ __launch_bounds__(BLK) void fin_k(const float* __restrict__ partial,
                                             const int* __restrict__ perm,
                                             float* __restrict__ out, int n, int nmax) {
    int si = blockIdx.x * BLK + threadIdx.x;
    if (si < n) {
        float p = 0.f;
        #pragma unroll
        for (int y = 0; y < YWK; ++y) p += partial[y * nmax + si];
        out[perm[si]] = logf(p + 1e-10f);
    }
}

extern "C" void kernel_launch(void* const* d_in, const int* in_sizes, int n_in,
                              void* d_out, int out_size, void* d_ws, size_t ws_size,
                              hipStream_t stream) {
    const float* d = (const float*)d_in[0];
    const float* w = (const float*)d_in[1];
    float* out = (float*)d_out;
    const int n = in_sizes[0];

    const int nmax = ((n + 255) / 256) * 256;   // 12032
    const int IB = nmax / 256;                  // 47

    // ws layout (float units): esw float2[nmax] | perm int[nmax] |
    //   params[16] | gcur int[NB] | tileJ int2[64] | partial[YWK*nmax]
    float*  wsf     = (float*)d_ws;
    float2* esw     = (float2*)wsf;
    int*    perm    = (int*)(wsf + 2 * nmax);
    float*  params  = wsf + 3 * nmax;
    int*    gcur    = (int*)(wsf + 3 * nmax + 16);
    int2*   tileJ   = (int2*)(wsf + 3 * nmax + 16 + NB);
    float*  partial = wsf + 3 * nmax + 16 + NB + 128;

    selA<<<1, 1024, 0, stream>>>(d, w, params, gcur, tileJ, n, nmax, IB);
    selB<<<IB, BLK, 0, stream>>>(d, w, params, gcur, esw, perm, n);
    dim3 grid(IB, YWK);
    kde_k<<<grid, BLK, 0, stream>>>(esw, tileJ, partial, n, nmax);
    fin_k<<<IB, BLK, 0, stream>>>(partial, perm, out, n, nmax);
}

// Round 17
// 30.772 us; speedup vs baseline: 1.8775x; 1.1874x over previous
//
#include <hip/hip_runtime.h>
#include <math.h>

// Gaussian KDE, n=12000. 3 dispatches, mean-matched BINNED KDE (1-level FGT):
//   k1 1x1024: stats+min/max; EXACT Q25/Q75 via value-linear 2048-bin int
//      histogram + candidate rank-select; h (float transcendentals); writes
//      params; zeroes gW/gWE accumulators.
//   k2 47x256: per-i float atomicAdd -> gW[b] += w_i, gWE[b] += w_i*d_i.
//   k3 188x256: stage (mu_e, W)[2048] in LDS; each block 64 i's x 4-way wave
//      split of the +-Delta bin window; pdf_i = sum_b W_b*exp2(-(e_i-mu_b)^2);
//      out[i] = log(pdf + 1e-10) in ORIGINAL order (no perm).
// Accuracy: mean-matched binning -> linear term vanishes; per-term rel err
//   <= 0.5*(k''/k)*(binwidth_e/2)^2 ~ 0.2% at u=CUT -> log err ~0.002
//   vs threshold 0.1625. Quantiles/h remain EXACT.

#define BLK 256
#define NB 2048
#define CAND 128
#define MAXN 12032
#define CUT 4.0f

#if defined(__has_builtin)
#if __has_builtin(__builtin_amdgcn_exp2f)
#define EXP2(x) __builtin_amdgcn_exp2f(x)
#endif
#endif
#ifndef EXP2
#define EXP2(x) exp2f(x)
#endif

// params: [0]=lo [1]=scale [2]=rr [3]=wsc
__global__ __launch_bounds__(1024) void k1(const float* __restrict__ d,
                                           const float* __restrict__ w,
                                           float* __restrict__ params,
                                           float* __restrict__ gW,
                                           float* __restrict__ gWE,
                                           int n) {
    __shared__ float sdata[MAXN];    // 48.1 KB
    __shared__ int hist[NB];         // 8 KB
    __shared__ int cum[NB];          // 8 KB
    __shared__ float cand[4][CAND];  // 2 KB
    __shared__ int ccnt[4];
    __shared__ int tb[4], tprev[4];
    __shared__ float4 sstat[16];
    __shared__ float2 smm[16];
    __shared__ int wtot[16];
    __shared__ float sq[4];
    __shared__ float slh[2];

    const int t = threadIdx.x, lane = t & 63, wid = t >> 6;

    for (int b = t; b < NB; b += 1024) { hist[b] = 0; gW[b] = 0.f; gWE[b] = 0.f; }
    if (t < 4) ccnt[t] = 0;

    // ---- pass 1: stage d; stats + min/max ----
    float s1 = 0.f, s2 = 0.f, sd = 0.f, sd2 = 0.f;
    float mn = __int_as_float(0x7f800000), mx = __int_as_float(0xff800000);
    for (int i = t; i < n; i += 1024) {
        float dv = d[i], wv = w[i];
        sdata[i] = dv;
        s1 += wv; s2 += wv * wv; sd += dv; sd2 += dv * dv;
        mn = fminf(mn, dv); mx = fmaxf(mx, dv);
    }
    for (int off = 32; off > 0; off >>= 1) {
        s1 += __shfl_down(s1, off); s2 += __shfl_down(s2, off);
        sd += __shfl_down(sd, off); sd2 += __shfl_down(sd2, off);
        mn = fminf(mn, __shfl_down(mn, off));
        mx = fmaxf(mx, __shfl_down(mx, off));
    }
    if (lane == 0) { sstat[wid] = make_float4(s1, s2, sd, sd2); smm[wid] = make_float2(mn, mx); }
    __syncthreads();
    if (t == 0) {
        float lo = smm[0].x, hi = smm[0].y;
        for (int q = 1; q < 16; ++q) { lo = fminf(lo, smm[q].x); hi = fmaxf(hi, smm[q].y); }
        slh[0] = lo; slh[1] = hi;
    }
    __syncthreads();
    const float lo = slh[0];
    const float range = slh[1] - lo;
    const float scale = (range > 0.f) ? (float)NB / range : 0.f;

    // ---- pass 2: value-linear int histogram ----
    for (int i = t; i < n; i += 1024) {
        int b = (int)((sdata[i] - lo) * scale);
        atomicAdd(&hist[b < NB ? b : NB - 1], 1);
    }
    __syncthreads();

    // ---- inclusive scan hist -> cum ----
    {
        const int b0 = t * 2;
        int a0 = hist[b0], a1 = hist[b0 + 1];
        int seg = a0 + a1, v = seg;
        for (int off = 1; off < 64; off <<= 1) {
            int u = __shfl_up(v, off);
            if (lane >= off) v += u;
        }
        if (lane == 63) wtot[wid] = v;
        __syncthreads();
        if (t == 0) {
            int acc = 0;
            for (int q = 0; q < 16; ++q) { int tmp = wtot[q]; wtot[q] = acc; acc += tmp; }
        }
        __syncthreads();
        int excl = wtot[wid] + (v - seg);
        cum[b0] = excl + a0;
        cum[b0 + 1] = excl + a0 + a1;
        __syncthreads();
    }

    // ---- quantile target bins ----
    const double p25 = 0.25 * (double)(n - 1);
    const double p75 = 0.75 * (double)(n - 1);
    const int l25 = (int)p25, l75 = (int)p75;
    const int u25 = (l25 + 1 < n) ? l25 + 1 : l25;
    const int u75 = (l75 + 1 < n) ? l75 + 1 : l75;
    const int targets[4] = {l25, u25, l75, u75};
    for (int b = t; b < NB; b += 1024) {
        int incl = cum[b], prev = b ? cum[b - 1] : 0;
        #pragma unroll
        for (int r = 0; r < 4; ++r)
            if (prev <= targets[r] && targets[r] < incl) { tb[r] = b; tprev[r] = prev; }
    }
    __syncthreads();

    // ---- candidates of target bins ----
    const int tb0 = tb[0], tb1 = tb[1], tb2 = tb[2], tb3 = tb[3];
    for (int i = t; i < n; i += 1024) {
        float dv = sdata[i];
        int b = (int)((dv - lo) * scale);
        b = b < NB ? b : NB - 1;
        if (b == tb0) { int p = atomicAdd(&ccnt[0], 1); if (p < CAND) cand[0][p] = dv; }
        if (b == tb1) { int p = atomicAdd(&ccnt[1], 1); if (p < CAND) cand[1][p] = dv; }
        if (b == tb2) { int p = atomicAdd(&ccnt[2], 1); if (p < CAND) cand[2][p] = dv; }
        if (b == tb3) { int p = atomicAdd(&ccnt[3], 1); if (p < CAND) cand[3][p] = dv; }
    }
    __syncthreads();

    // ---- exact rank-select (wave r per target): kk-th smallest of multiset ----
    if (wid < 4) {
        const int r = wid;
        const int kk = targets[r] - tprev[r];
        const int m = ccnt[r] < CAND ? ccnt[r] : CAND;
        for (int ci = lane; ci < m; ci += 64) {
            float v = cand[r][ci];
            int rk = 0, eqb = 0;
            for (int j = 0; j < m; ++j) {
                float u = cand[r][j];
                rk += (u < v);
                eqb += (u == v && j < ci);
            }
            if (rk + eqb == kk) sq[r] = v;
        }
    }
    __syncthreads();

    // ---- h + scales (float transcendentals; double only for sums) ----
    if (t == 0) {
        double S1 = 0, S2 = 0, Sd = 0, Sd2 = 0;
        for (int q = 0; q < 16; ++q) {
            float4 v = sstat[q];
            S1 += v.x; S2 += v.y; Sd += v.z; Sd2 += v.w;
        }
        float neff = (float)(S1 * S1 / S2);
        float varf = (float)((Sd2 - Sd * Sd / (double)n) / ((double)n - 1.0));
        float sdev = sqrtf(varf);
        float f25 = (float)(p25 - (double)l25), f75 = (float)(p75 - (double)l75);
        float q25 = sq[0] + f25 * (sq[1] - sq[0]);
        float q75 = sq[2] + f75 * (sq[3] - sq[2]);
        float sig = fminf(sdev, (q75 - q25) * (1.0f / 1.34f));
        float h = 0.9f * sig * exp2f(-0.2f * log2f(neff));
        float rr = 0.84932180f / h;                        // sqrt(0.5*log2(e))/h
        params[0] = lo; params[1] = scale;
        params[2] = rr;
        params[3] = 1.0f / (h * 2.50662827f * (float)S1);  // inv_norm / S1
    }
}

__global__ __launch_bounds__(BLK) void k2(const float* __restrict__ d,
                                          const float* __restrict__ w,
                                          const float* __restrict__ params,
                                          float* __restrict__ gW,
                                          float* __restrict__ gWE,
                                          int n) {
    const int i = blockIdx.x * BLK + threadIdx.x;
    if (i >= n) return;
    const float lo = params[0], scale = params[1];
    float dv = d[i], wv = w[i];
    int b = (int)((dv - lo) * scale);
    b = b < NB ? b : NB - 1;
    atomicAdd(&gW[b], wv);          // device float atomics, spread over 47 CUs
    atomicAdd(&gWE[b], wv * dv);
}

__global__ __launch_bounds__(BLK) void k3(const float* __restrict__ d,
                                          const float* __restrict__ params,
                                          const float* __restrict__ gW,
                                          const float* __restrict__ gWE,
                                          float* __restrict__ out, int n) {
    __shared__ float2 sb[NB];     // (mu_e, W) per bin, 16 KB
    __shared__ float sred[BLK];   // 1 KB
    const int t = threadIdx.x, lane = t & 63, wv = t >> 6;
    const float lo = params[0], scale = params[1], rr = params[2], wsc = params[3];

    for (int idx = t; idx < NB; idx += BLK) {
        float aw = gW[idx], awe = gWE[idx];
        float mu = (aw > 0.f) ? (awe / aw) : 0.f;   // guard: W=0 -> finite mu
        sb[idx] = make_float2(mu * rr, aw * wsc);
    }

    const int i = blockIdx.x * 64 + lane;
    const float di = (i < n) ? d[i] : 0.f;
    const float ei = di * rr;
    int bi = (int)((di - lo) * scale);
    bi = bi < NB ? bi : NB - 1; if (bi < 0) bi = 0;
    const int delta = (scale > 0.f && rr > 0.f)
                      ? (int)ceilf(CUT * scale / rr) + 1 : NB;
    int b0 = bi - delta; if (b0 < 0) b0 = 0;
    int b1 = bi + delta; if (b1 > NB - 1) b1 = NB - 1;
    const int len = b1 - b0 + 1;
    const int q = (len + 3) >> 2;          // quarter per wave
    int s = b0 + wv * q;
    int e = s + q; if (e > b1 + 1) e = b1 + 1;

    __syncthreads();                        // sb staged

    float acc0 = 0.f, acc1 = 0.f;
    int b = s;
    for (; b + 1 < e; b += 2) {
        float2 p0 = sb[b], p1 = sb[b + 1];
        float u0 = ei - p0.x, u1 = ei - p1.x;
        acc0 = fmaf(p0.y, EXP2(-(u0 * u0)), acc0);
        acc1 = fmaf(p1.y, EXP2(-(u1 * u1)), acc1);
    }
    if (b < e) {
        float2 p0 = sb[b];
        float u0 = ei - p0.x;
        acc0 = fmaf(p0.y, EXP2(-(u0 * u0)), acc0);
    }

    sred[wv * 64 + lane] = acc0 + acc1;
    __syncthreads();
    if (t < 64) {
        int ii = blockIdx.x * 64 + t;
        if (ii < n) {
            float p = sred[t] + sred[64 + t] + sred[128 + t] + sred[192 + t];
            out[ii] = logf(p + 1e-10f);
        }
    }
}

extern "C" void kernel_launch(void* const* d_in, const int* in_sizes, int n_in,
                              void* d_out, int out_size, void* d_ws, size_t ws_size,
                              hipStream_t stream) {
    const float* d = (const float*)d_in[0];
    const float* w = (const float*)d_in[1];
    float* out = (float*)d_out;
    const int n = in_sizes[0];

    const int nmax = ((n + 255) / 256) * 256;   // 12032
    const int IB = nmax / 256;                  // 47
    const int G3 = nmax / 64;                   // 188

    // ws layout (floats): params[16] | gW[NB] | gWE[NB]
    float* wsf    = (float*)d_ws;
    float* params = wsf;
    float* gW     = wsf + 16;
    float* gWE    = wsf + 16 + NB;

    k1<<<1, 1024, 0, stream>>>(d, w, params, gW, gWE, n);
    k2<<<IB, BLK, 0, stream>>>(d, w, params, gW, gWE, n);
    k3<<<G3, BLK, 0, stream>>>(d, params, gW, gWE, out, n);
}